// Round 5
// baseline (1202.056 us; speedup 1.0000x reference)
//
#include <hip/hip_runtime.h>
#include <hip/hip_cooperative_groups.h>
#include <cmath>
#include <cstdint>

namespace cg = cooperative_groups;

#define N_F    2000
#define N_I    500
#define N_O    500
#define N_ALL  3000
#define C      8
#define H      16000
#define B      256
#define E_FF   40000
#define E_IF   5000
#define E_FO   2000
#define E_ALL  47000
#define LAYERS 10
#define EPSF   1e-5f
#define NBLK   500
#define NPB    4      // nodes per block (NBLK*NPB == N_F)

// ---------------- CSR build (deterministic after k_sort) ----------------

__global__ void k_zero_cnt(int* cntA, int* cntB, int* cntC, int* cntD) {
    int tid = threadIdx.x;
    for (int i = tid; i < N_F; i += 1024) { cntA[i] = 0; cntB[i] = 0; cntC[i] = 0; }
    for (int i = tid; i < N_O; i += 1024) cntD[i] = 0;
}

__global__ void k_count(const int* __restrict__ src, const int* __restrict__ dst,
                        int* cntA, int* cntB, int* cntC, int* cntD) {
    int e = blockIdx.x * 256 + threadIdx.x;
    if (e >= E_ALL) return;
    int s = src[e], d = dst[e];
    if (e < E_FF)             { atomicAdd(&cntA[d], 1); atomicAdd(&cntB[d], 1); atomicAdd(&cntC[s], 1); }
    else if (e < E_FF + E_IF) { atomicAdd(&cntA[d], 1); }
    else                      { atomicAdd(&cntD[d - (N_F + N_I)], 1); }
}

// 4 single-block scans: A(dst,FF+IF), B(dst,FF), C(src,FF), D(dst,FO)
__global__ void k_scan(const int* cntA, const int* cntB, const int* cntC, const int* cntD,
                       int* rsA, int* rsB, int* rsC, int* rsD,
                       int* curA, int* curB, int* curC, int* curD) {
    const int* cnt; int* rs; int* cur; int len;
    if      (blockIdx.x == 0) { cnt = cntA; rs = rsA; cur = curA; len = N_F; }
    else if (blockIdx.x == 1) { cnt = cntB; rs = rsB; cur = curB; len = N_F; }
    else if (blockIdx.x == 2) { cnt = cntC; rs = rsC; cur = curC; len = N_F; }
    else                      { cnt = cntD; rs = rsD; cur = curD; len = N_O; }
    __shared__ int buf[1024];
    __shared__ int carry;
    int tid = threadIdx.x;
    if (tid == 0) carry = 0;
    __syncthreads();
    for (int base0 = 0; base0 < len; base0 += 1024) {
        int i = base0 + tid;
        int v = (i < len) ? cnt[i] : 0;
        buf[tid] = v;
        __syncthreads();
        for (int off = 1; off < 1024; off <<= 1) {
            int t = (tid >= off) ? buf[tid - off] : 0;
            __syncthreads();
            buf[tid] += t;
            __syncthreads();
        }
        int excl = carry + buf[tid] - v;
        if (i < len) { rs[i] = excl; cur[i] = excl; }
        int tot = buf[1023];
        __syncthreads();
        if (tid == 0) carry += tot;
        __syncthreads();
    }
    if (tid == 0) rs[len] = carry;
}

__global__ void k_fill(const int* __restrict__ src, const int* __restrict__ dst,
                       int* curA, int* curB, int* curC, int* curD,
                       int* eidA, int* eidB, int* eidC, int* eidD) {
    int e = blockIdx.x * 256 + threadIdx.x;
    if (e >= E_ALL) return;
    int s = src[e], d = dst[e];
    if (e < E_FF) {
        int a = atomicAdd(&curA[d], 1); eidA[a] = e;
        int j = atomicAdd(&curB[d], 1); eidB[j] = e;
        int p = atomicAdd(&curC[s], 1); eidC[p] = e;
    } else if (e < E_FF + E_IF) {
        int a = atomicAdd(&curA[d], 1); eidA[a] = e;
    } else {
        int k = atomicAdd(&curD[d - (N_F + N_I)], 1); eidD[k] = e;
    }
}

// canonicalize: sort each adjacency list ascending by edge id (insertion sort)
__global__ void k_sort(const int* rsA, int* eidA, const int* rsB, int* eidB,
                       const int* rsC, int* eidC, const int* rsD, int* eidD) {
    int t = blockIdx.x * 256 + threadIdx.x;
    const int* rs; int* eid; int n;
    if      (t < 2000) { rs = rsA; eid = eidA; n = t; }
    else if (t < 4000) { rs = rsB; eid = eidB; n = t - 2000; }
    else if (t < 6000) { rs = rsC; eid = eidC; n = t - 4000; }
    else if (t < 6500) { rs = rsD; eid = eidD; n = t - 6000; }
    else return;
    int beg = rs[n], end = rs[n + 1];
    for (int i = beg + 1; i < end; ++i) {
        int key = eid[i];
        int j = i - 1;
        while (j >= beg && eid[j] > key) { eid[j + 1] = eid[j]; --j; }
        eid[j + 1] = key;
    }
}

// ---------------- init ----------------

// x (B, N_ALL) -> xT (N_ALL, B)
__global__ void k_xT(const float* __restrict__ x, float* __restrict__ xT) {
    __shared__ float t[32][33];
    int tx = threadIdx.x, ty = threadIdx.y;
    int n = blockIdx.x * 32 + tx, b = blockIdx.y * 32 + ty;
    if (n < N_ALL) t[ty][tx] = x[b * N_ALL + n];
    __syncthreads();
    int n2 = blockIdx.x * 32 + ty, b2 = blockIdx.y * 32 + tx;
    if (n2 < N_ALL) xT[n2 * B + b2] = t[tx][ty];
}

// base[n][c][b] = sum_{FF+IF e->n} w1[e][c]*x[src_e][b] + b1[n*C+c]; bb[n][c] = sum w1[e][c]*b2[e]
__global__ void k_base(const float* __restrict__ xT, const float* __restrict__ w1,
                       const float* __restrict__ b1, const float* __restrict__ b2,
                       const int* __restrict__ rsA, const int* __restrict__ eidA,
                       const int* __restrict__ srcv,
                       float* __restrict__ baseG, float* __restrict__ bbG) {
    int n = blockIdx.x, tid = threadIdx.x;
    int beg = rsA[n], end = rsA[n + 1];
    float acc[C] = {0.f,0.f,0.f,0.f,0.f,0.f,0.f,0.f};
    float bba[C] = {0.f,0.f,0.f,0.f,0.f,0.f,0.f,0.f};
    const float4* w14 = (const float4*)w1;
    for (int a = beg; a < end; ++a) {
        int e = eidA[a];
        float xv = xT[srcv[e] * B + tid];
        float bv = b2[e];
        float4 u0 = w14[e * 2], u1 = w14[e * 2 + 1];
        acc[0] += u0.x * xv; acc[1] += u0.y * xv; acc[2] += u0.z * xv; acc[3] += u0.w * xv;
        acc[4] += u1.x * xv; acc[5] += u1.y * xv; acc[6] += u1.z * xv; acc[7] += u1.w * xv;
        bba[0] += u0.x * bv; bba[1] += u0.y * bv; bba[2] += u0.z * bv; bba[3] += u0.w * bv;
        bba[4] += u1.x * bv; bba[5] += u1.y * bv; bba[6] += u1.z * bv; bba[7] += u1.w * bv;
    }
    #pragma unroll
    for (int c = 0; c < C; ++c) baseG[(n * C + c) * B + tid] = acc[c] + b1[n * C + c];
    if (tid == 0) {
        #pragma unroll
        for (int c = 0; c < C; ++c) bbG[n * C + c] = bba[c];
    }
}

// ---------------- cooperative recurrence ----------------
// hid_t[n] = base[n] + t*bb[n] + sum_{FF e->n} w1[e]*q_t[e],  q_t[e] = w2[e].S_t[src_e]
// S_t = sum over layers < t of normalized+ELU hidden. S, hid in registers; base/bb/q in global.

__global__ __launch_bounds__(256, 2) void k_coop(
    const float* __restrict__ xT, const float* __restrict__ w1,
    const float* __restrict__ gamma, const float* __restrict__ beta,
    const float* __restrict__ w2, const float* __restrict__ b2,
    const int* __restrict__ srcv,
    const int* __restrict__ rsB, const int* __restrict__ eidB,
    const int* __restrict__ rsC, const int* __restrict__ eidC,
    const int* __restrict__ rsD, const int* __restrict__ eidD,
    const float* __restrict__ baseG, const float* __restrict__ bbG,
    float* __restrict__ q, float* __restrict__ bp, float* __restrict__ p2,
    float* __restrict__ Sg, float* __restrict__ out)
{
    cg::grid_group grid = cg::this_grid();
    const int blk = blockIdx.x, tid = threadIdx.x;
    const float4* w14 = (const float4*)w1;
    const float4* w24 = (const float4*)w2;

    // zero d_out (harness re-poisons it before every timed call): 500*1536 = 768000 floats
    #pragma unroll
    for (int k2 = 0; k2 < 6; ++k2) out[blk * 1536 + k2 * 256 + tid] = 0.f;

    float Sreg[NPB][C], hidR[NPB][C];

    for (int t = 0; t < LAYERS; ++t) {
        float tf = (float)t;
        // phase A: hid into registers + per-block stat partials
        float s1 = 0.f, s2 = 0.f;
        for (int u = 0; u < NPB; ++u) {
            int n = blk * NPB + u;
            #pragma unroll
            for (int c = 0; c < C; ++c)
                hidR[u][c] = baseG[(n * C + c) * B + tid] + tf * bbG[n * C + c];
            if (t > 0) {
                int beg = rsB[n], end = rsB[n + 1];
                for (int j = beg; j < end; ++j) {
                    int e = eidB[j];
                    float qv = q[e * B + tid];
                    float4 u0 = w14[e * 2], u1 = w14[e * 2 + 1];
                    hidR[u][0] += u0.x * qv; hidR[u][1] += u0.y * qv;
                    hidR[u][2] += u0.z * qv; hidR[u][3] += u0.w * qv;
                    hidR[u][4] += u1.x * qv; hidR[u][5] += u1.y * qv;
                    hidR[u][6] += u1.z * qv; hidR[u][7] += u1.w * qv;
                }
            }
            #pragma unroll
            for (int c = 0; c < C; ++c) { s1 += hidR[u][c]; s2 += hidR[u][c] * hidR[u][c]; }
        }
        bp[(blk * 2 + 0) * B + tid] = s1;
        bp[(blk * 2 + 1) * B + tid] = s2;
        grid.sync();

        // phase B: 8 blocks reduce NBLK block-partials -> 8
        if (blk < 8) {
            float a1 = 0.f, a2 = 0.f;
            for (int i = blk; i < NBLK; i += 8) {
                a1 += bp[(i * 2 + 0) * B + tid];
                a2 += bp[(i * 2 + 1) * B + tid];
            }
            p2[(blk * 2 + 0) * B + tid] = a1;
            p2[(blk * 2 + 1) * B + tid] = a2;
        }
        grid.sync();

        // phase C: finalize stats, normalize+ELU, S += h, emit q (or Sg at last layer)
        float S1 = 0.f, S2 = 0.f;
        #pragma unroll
        for (int k = 0; k < 8; ++k) {
            S1 += p2[(k * 2 + 0) * B + tid];
            S2 += p2[(k * 2 + 1) * B + tid];
        }
        float mu  = S1 * (1.0f / H);
        float var = S2 * (1.0f / H) - mu * mu;
        float rsq = rsqrtf(var + EPSF);
        for (int u = 0; u < NPB; ++u) {
            int n = blk * NPB + u;
            #pragma unroll
            for (int c = 0; c < C; ++c) {
                float v = (hidR[u][c] - mu) * rsq * gamma[n * C + c] + beta[n * C + c];
                v = (v > 0.f) ? v : expm1f(v);
                Sreg[u][c] = (t == 0) ? v : (Sreg[u][c] + v);
            }
            if (t < LAYERS - 1) {
                int beg = rsC[n], end = rsC[n + 1];
                for (int p = beg; p < end; ++p) {
                    int e = eidC[p];
                    float4 u0 = w24[e * 2], u1 = w24[e * 2 + 1];
                    float qv = u0.x * Sreg[u][0] + u0.y * Sreg[u][1] + u0.z * Sreg[u][2] + u0.w * Sreg[u][3]
                             + u1.x * Sreg[u][4] + u1.y * Sreg[u][5] + u1.z * Sreg[u][6] + u1.w * Sreg[u][7];
                    q[e * B + tid] = qv;
                }
            } else {
                #pragma unroll
                for (int c = 0; c < C; ++c) Sg[(n * C + c) * B + tid] = Sreg[u][c];
            }
        }
        grid.sync();
    }

    // output: out[b][n_out] = (1/L) sum_{FO e->n} (x[src]+Sg[src].w2[e]+L*b2[e]); blk == o < 500
    {
        int o = blk;
        float acc = 0.f;
        int beg = rsD[o], end = rsD[o + 1];
        for (int k = beg; k < end; ++k) {
            int e = eidD[k];
            int s = srcv[e];
            float4 u0 = w24[e * 2], u1 = w24[e * 2 + 1];
            float dot = u0.x * Sg[(s * C + 0) * B + tid] + u0.y * Sg[(s * C + 1) * B + tid]
                      + u0.z * Sg[(s * C + 2) * B + tid] + u0.w * Sg[(s * C + 3) * B + tid]
                      + u1.x * Sg[(s * C + 4) * B + tid] + u1.y * Sg[(s * C + 5) * B + tid]
                      + u1.z * Sg[(s * C + 6) * B + tid] + u1.w * Sg[(s * C + 7) * B + tid];
            acc += xT[s * B + tid] + dot + (float)LAYERS * b2[e];
        }
        out[tid * N_ALL + (N_F + N_I + o)] = acc * (1.0f / LAYERS);
    }
}

// ---------------- fallback (non-cooperative) per-layer pipeline ----------------

__global__ void f_hidstat(const float* __restrict__ baseG, const float* __restrict__ bbG,
                          const float* __restrict__ w1, const float* __restrict__ q,
                          const int* __restrict__ rsB, const int* __restrict__ eidB,
                          float* __restrict__ hidG, float* __restrict__ bp, int t) {
    int blk = blockIdx.x, tid = threadIdx.x;
    const float4* w14 = (const float4*)w1;
    float tf = (float)t;
    float s1 = 0.f, s2 = 0.f;
    for (int u = 0; u < NPB; ++u) {
        int n = blk * NPB + u;
        float hid[C];
        #pragma unroll
        for (int c = 0; c < C; ++c) hid[c] = baseG[(n * C + c) * B + tid] + tf * bbG[n * C + c];
        if (t > 0) {
            int beg = rsB[n], end = rsB[n + 1];
            for (int j = beg; j < end; ++j) {
                int e = eidB[j];
                float qv = q[e * B + tid];
                float4 u0 = w14[e * 2], u1 = w14[e * 2 + 1];
                hid[0] += u0.x * qv; hid[1] += u0.y * qv; hid[2] += u0.z * qv; hid[3] += u0.w * qv;
                hid[4] += u1.x * qv; hid[5] += u1.y * qv; hid[6] += u1.z * qv; hid[7] += u1.w * qv;
            }
        }
        #pragma unroll
        for (int c = 0; c < C; ++c) {
            hidG[(n * C + c) * B + tid] = hid[c];
            s1 += hid[c]; s2 += hid[c] * hid[c];
        }
    }
    bp[(blk * 2 + 0) * B + tid] = s1;
    bp[(blk * 2 + 1) * B + tid] = s2;
}

__global__ void f_red(const float* __restrict__ bp, float* __restrict__ p2) {
    int blk = blockIdx.x, tid = threadIdx.x;
    float a1 = 0.f, a2 = 0.f;
    for (int i = blk; i < NBLK; i += 8) {
        a1 += bp[(i * 2 + 0) * B + tid];
        a2 += bp[(i * 2 + 1) * B + tid];
    }
    p2[(blk * 2 + 0) * B + tid] = a1;
    p2[(blk * 2 + 1) * B + tid] = a2;
}

__global__ void f_upd(const float* __restrict__ hidG, const float* __restrict__ p2,
                      const float* __restrict__ gamma, const float* __restrict__ beta,
                      const float* __restrict__ w2, const int* __restrict__ rsC,
                      const int* __restrict__ eidC,
                      float* __restrict__ Sg, float* __restrict__ q, int t) {
    int blk = blockIdx.x, tid = threadIdx.x;
    const float4* w24 = (const float4*)w2;
    float S1 = 0.f, S2 = 0.f;
    #pragma unroll
    for (int k = 0; k < 8; ++k) {
        S1 += p2[(k * 2 + 0) * B + tid];
        S2 += p2[(k * 2 + 1) * B + tid];
    }
    float mu  = S1 * (1.0f / H);
    float var = S2 * (1.0f / H) - mu * mu;
    float rsq = rsqrtf(var + EPSF);
    for (int u = 0; u < NPB; ++u) {
        int n = blk * NPB + u;
        float Sn[C];
        #pragma unroll
        for (int c = 0; c < C; ++c) {
            float v = (hidG[(n * C + c) * B + tid] - mu) * rsq * gamma[n * C + c] + beta[n * C + c];
            v = (v > 0.f) ? v : expm1f(v);
            Sn[c] = (t == 0) ? v : (Sg[(n * C + c) * B + tid] + v);
        }
        #pragma unroll
        for (int c = 0; c < C; ++c) Sg[(n * C + c) * B + tid] = Sn[c];
        if (t < LAYERS - 1) {
            int beg = rsC[n], end = rsC[n + 1];
            for (int p = beg; p < end; ++p) {
                int e = eidC[p];
                float4 u0 = w24[e * 2], u1 = w24[e * 2 + 1];
                float qv = u0.x * Sn[0] + u0.y * Sn[1] + u0.z * Sn[2] + u0.w * Sn[3]
                         + u1.x * Sn[4] + u1.y * Sn[5] + u1.z * Sn[6] + u1.w * Sn[7];
                q[e * B + tid] = qv;
            }
        }
    }
}

__global__ void f_zero_out(float* __restrict__ out) {
    int i = blockIdx.x * 256 + threadIdx.x;  // 750*256 float4 = 768000 floats
    ((float4*)out)[i] = make_float4(0.f, 0.f, 0.f, 0.f);
}

__global__ void f_out(const float* __restrict__ xT, const float* __restrict__ Sg,
                      const int* __restrict__ rsD, const int* __restrict__ eidD,
                      const int* __restrict__ srcv, const float* __restrict__ w2,
                      const float* __restrict__ b2, float* __restrict__ out) {
    int o = blockIdx.x, tid = threadIdx.x;
    const float4* w24 = (const float4*)w2;
    float acc = 0.f;
    int beg = rsD[o], end = rsD[o + 1];
    for (int k = beg; k < end; ++k) {
        int e = eidD[k];
        int s = srcv[e];
        float4 u0 = w24[e * 2], u1 = w24[e * 2 + 1];
        float dot = u0.x * Sg[(s * C + 0) * B + tid] + u0.y * Sg[(s * C + 1) * B + tid]
                  + u0.z * Sg[(s * C + 2) * B + tid] + u0.w * Sg[(s * C + 3) * B + tid]
                  + u1.x * Sg[(s * C + 4) * B + tid] + u1.y * Sg[(s * C + 5) * B + tid]
                  + u1.z * Sg[(s * C + 6) * B + tid] + u1.w * Sg[(s * C + 7) * B + tid];
        acc += xT[s * B + tid] + dot + (float)LAYERS * b2[e];
    }
    out[tid * N_ALL + (N_F + N_I + o)] = acc * (1.0f / LAYERS);
}

// ---------------- launch ----------------

static inline char* alignup(char* p) { return (char*)(((uintptr_t)p + 255) & ~(uintptr_t)255); }

extern "C" void kernel_launch(void* const* d_in, const int* in_sizes, int n_in,
                              void* d_out, int out_size, void* d_ws, size_t ws_size,
                              hipStream_t stream) {
    const float* x     = (const float*)d_in[0];
    const float* w1    = (const float*)d_in[1];
    const float* b1    = (const float*)d_in[2];
    const float* gamma = (const float*)d_in[3];
    const float* beta  = (const float*)d_in[4];
    const float* w2    = (const float*)d_in[5];
    const float* b2    = (const float*)d_in[6];
    const int*   ei    = (const int*)d_in[7];
    const int* srcv = ei;
    const int* dstv = ei + E_ALL;
    float* out = (float*)d_out;

    char* p = (char*)d_ws;
    float* q     = (float*)p; p += (size_t)E_FF * B * 4;    p = alignup(p);
    float* Sg    = (float*)p; p += (size_t)H * B * 4;       p = alignup(p);
    float* baseG = (float*)p; p += (size_t)H * B * 4;       p = alignup(p);
    float* hidG  = (float*)p; p += (size_t)H * B * 4;       p = alignup(p);   // fallback only
    float* xT    = (float*)p; p += (size_t)N_ALL * B * 4;   p = alignup(p);
    float* bp    = (float*)p; p += (size_t)NBLK * 2 * B * 4; p = alignup(p);
    float* p2    = (float*)p; p += 8 * 2 * B * 4;           p = alignup(p);
    float* bbG   = (float*)p; p += (size_t)N_F * C * 4;     p = alignup(p);
    int* cntA = (int*)p; p += N_F * 4;        p = alignup(p);
    int* cntB = (int*)p; p += N_F * 4;        p = alignup(p);
    int* cntC = (int*)p; p += N_F * 4;        p = alignup(p);
    int* cntD = (int*)p; p += N_O * 4;        p = alignup(p);
    int* curA = (int*)p; p += N_F * 4;        p = alignup(p);
    int* curB = (int*)p; p += N_F * 4;        p = alignup(p);
    int* curC = (int*)p; p += N_F * 4;        p = alignup(p);
    int* curD = (int*)p; p += N_O * 4;        p = alignup(p);
    int* rsA  = (int*)p; p += (N_F + 1) * 4;  p = alignup(p);
    int* rsB  = (int*)p; p += (N_F + 1) * 4;  p = alignup(p);
    int* rsC  = (int*)p; p += (N_F + 1) * 4;  p = alignup(p);
    int* rsD  = (int*)p; p += (N_O + 1) * 4;  p = alignup(p);
    int* eidA = (int*)p; p += (size_t)(E_FF + E_IF) * 4; p = alignup(p);
    int* eidB = (int*)p; p += (size_t)E_FF * 4; p = alignup(p);
    int* eidC = (int*)p; p += (size_t)E_FF * 4; p = alignup(p);
    int* eidD = (int*)p; p += (size_t)E_FO * 4; p = alignup(p);

    hipLaunchKernelGGL(k_zero_cnt, dim3(1), dim3(1024), 0, stream, cntA, cntB, cntC, cntD);
    hipLaunchKernelGGL(k_count, dim3((E_ALL + 255) / 256), dim3(256), 0, stream,
                       srcv, dstv, cntA, cntB, cntC, cntD);
    hipLaunchKernelGGL(k_scan, dim3(4), dim3(1024), 0, stream,
                       cntA, cntB, cntC, cntD, rsA, rsB, rsC, rsD, curA, curB, curC, curD);
    hipLaunchKernelGGL(k_fill, dim3((E_ALL + 255) / 256), dim3(256), 0, stream,
                       srcv, dstv, curA, curB, curC, curD, eidA, eidB, eidC, eidD);
    hipLaunchKernelGGL(k_sort, dim3(26), dim3(256), 0, stream,
                       rsA, eidA, rsB, eidB, rsC, eidC, rsD, eidD);
    hipLaunchKernelGGL(k_xT, dim3((N_ALL + 31) / 32, B / 32), dim3(32, 32), 0, stream, x, xT);
    hipLaunchKernelGGL(k_base, dim3(N_F), dim3(256), 0, stream,
                       xT, w1, b1, b2, rsA, eidA, srcv, baseG, bbG);

    // deterministic host-side path choice (pure queries; capture-safe)
    int dev = 0;
    (void)hipGetDevice(&dev);
    int numCU = 0;
    (void)hipDeviceGetAttribute(&numCU, hipDeviceAttributeMultiprocessorCount, dev);
    int maxPerCU = 0;
    (void)hipOccupancyMaxActiveBlocksPerMultiprocessor(&maxPerCU, (const void*)k_coop, 256, 0);
    bool coop_ok = (maxPerCU > 0) && ((long)maxPerCU * (long)numCU >= NBLK);

    if (coop_ok) {
        void* args[] = {
            (void*)&xT, (void*)&w1, (void*)&gamma, (void*)&beta,
            (void*)&w2, (void*)&b2, (void*)&srcv,
            (void*)&rsB, (void*)&eidB, (void*)&rsC, (void*)&eidC,
            (void*)&rsD, (void*)&eidD, (void*)&baseG, (void*)&bbG,
            (void*)&q, (void*)&bp, (void*)&p2, (void*)&Sg, (void*)&out
        };
        hipLaunchCooperativeKernel((void*)k_coop, dim3(NBLK), dim3(256), args, 0, stream);
    } else {
        hipLaunchKernelGGL(f_zero_out, dim3(750), dim3(256), 0, stream, out);
        for (int t = 0; t < LAYERS; ++t) {
            hipLaunchKernelGGL(f_hidstat, dim3(NBLK), dim3(256), 0, stream,
                               baseG, bbG, w1, q, rsB, eidB, hidG, bp, t);
            hipLaunchKernelGGL(f_red, dim3(8), dim3(256), 0, stream, bp, p2);
            hipLaunchKernelGGL(f_upd, dim3(NBLK), dim3(256), 0, stream,
                               hidG, p2, gamma, beta, w2, rsC, eidC, Sg, q, t);
        }
        hipLaunchKernelGGL(f_out, dim3(N_O), dim3(256), 0, stream,
                           xT, Sg, rsD, eidD, srcv, w2, b2, out);
    }
}

// Round 6
// 1168.184 us; speedup vs baseline: 1.0290x; 1.0290x over previous
//
#include <hip/hip_runtime.h>
#include <cmath>
#include <cstdint>

#define N_F    2000
#define N_I    500
#define N_O    500
#define N_ALL  3000
#define C      8
#define H      16000
#define B      256
#define E_FF   40000
#define E_IF   5000
#define E_FO   2000
#define E_ALL  47000
#define LAYERS 10
#define EPSF   1e-5f
#define NBLK   500
#define NPB    4      // nodes per block (NBLK*NPB == N_F)

// ---- bf16 helpers (RNE) ----
static __device__ __forceinline__ unsigned short f2bf(float f) {
    unsigned int u = __float_as_uint(f);
    unsigned int r = (u + 0x7FFFu + ((u >> 16) & 1u)) >> 16;
    return (unsigned short)r;
}
static __device__ __forceinline__ float bf2f(unsigned short h) {
    return __uint_as_float(((unsigned int)h) << 16);
}

// ---------------- CSR build (deterministic after k_sort) ----------------

__global__ void k_zero_cnt(int* cntA, int* cntB, int* cntC, int* cntD) {
    int tid = threadIdx.x;
    for (int i = tid; i < N_F; i += 1024) { cntA[i] = 0; cntB[i] = 0; cntC[i] = 0; }
    for (int i = tid; i < N_O; i += 1024) cntD[i] = 0;
}

__global__ void k_count(const int* __restrict__ src, const int* __restrict__ dst,
                        int* cntA, int* cntB, int* cntC, int* cntD) {
    int e = blockIdx.x * 256 + threadIdx.x;
    if (e >= E_ALL) return;
    int s = src[e], d = dst[e];
    if (e < E_FF)             { atomicAdd(&cntA[d], 1); atomicAdd(&cntB[d], 1); atomicAdd(&cntC[s], 1); }
    else if (e < E_FF + E_IF) { atomicAdd(&cntA[d], 1); }
    else                      { atomicAdd(&cntD[d - (N_F + N_I)], 1); }
}

// 4 single-block scans: A(dst,FF+IF), B(dst,FF), C(src,FF), D(dst,FO)
__global__ void k_scan(const int* cntA, const int* cntB, const int* cntC, const int* cntD,
                       int* rsA, int* rsB, int* rsC, int* rsD,
                       int* curA, int* curB, int* curC, int* curD) {
    const int* cnt; int* rs; int* cur; int len;
    if      (blockIdx.x == 0) { cnt = cntA; rs = rsA; cur = curA; len = N_F; }
    else if (blockIdx.x == 1) { cnt = cntB; rs = rsB; cur = curB; len = N_F; }
    else if (blockIdx.x == 2) { cnt = cntC; rs = rsC; cur = curC; len = N_F; }
    else                      { cnt = cntD; rs = rsD; cur = curD; len = N_O; }
    __shared__ int buf[1024];
    __shared__ int carry;
    int tid = threadIdx.x;
    if (tid == 0) carry = 0;
    __syncthreads();
    for (int base0 = 0; base0 < len; base0 += 1024) {
        int i = base0 + tid;
        int v = (i < len) ? cnt[i] : 0;
        buf[tid] = v;
        __syncthreads();
        for (int off = 1; off < 1024; off <<= 1) {
            int t = (tid >= off) ? buf[tid - off] : 0;
            __syncthreads();
            buf[tid] += t;
            __syncthreads();
        }
        int excl = carry + buf[tid] - v;
        if (i < len) { rs[i] = excl; cur[i] = excl; }
        int tot = buf[1023];
        __syncthreads();
        if (tid == 0) carry += tot;
        __syncthreads();
    }
    if (tid == 0) rs[len] = carry;
}

__global__ void k_fill(const int* __restrict__ src, const int* __restrict__ dst,
                       int* curA, int* curB, int* curC, int* curD,
                       int* eidA, int* eidB, int* eidC, int* eidD) {
    int e = blockIdx.x * 256 + threadIdx.x;
    if (e >= E_ALL) return;
    int s = src[e], d = dst[e];
    if (e < E_FF) {
        int a = atomicAdd(&curA[d], 1); eidA[a] = e;
        int j = atomicAdd(&curB[d], 1); eidB[j] = e;
        int p = atomicAdd(&curC[s], 1); eidC[p] = e;
    } else if (e < E_FF + E_IF) {
        int a = atomicAdd(&curA[d], 1); eidA[a] = e;
    } else {
        int k = atomicAdd(&curD[d - (N_F + N_I)], 1); eidD[k] = e;
    }
}

// canonicalize: sort each adjacency list ascending by edge id (insertion sort)
__global__ void k_sort(const int* rsA, int* eidA, const int* rsB, int* eidB,
                       const int* rsC, int* eidC, const int* rsD, int* eidD) {
    int t = blockIdx.x * 256 + threadIdx.x;
    const int* rs; int* eid; int n;
    if      (t < 2000) { rs = rsA; eid = eidA; n = t; }
    else if (t < 4000) { rs = rsB; eid = eidB; n = t - 2000; }
    else if (t < 6000) { rs = rsC; eid = eidC; n = t - 4000; }
    else if (t < 6500) { rs = rsD; eid = eidD; n = t - 6000; }
    else return;
    int beg = rs[n], end = rs[n + 1];
    for (int i = beg + 1; i < end; ++i) {
        int key = eid[i];
        int j = i - 1;
        while (j >= beg && eid[j] > key) { eid[j + 1] = eid[j]; --j; }
        eid[j + 1] = key;
    }
}

// ---------------- init ----------------

// x (B, N_ALL) -> xT (N_ALL, B)
__global__ void k_xT(const float* __restrict__ x, float* __restrict__ xT) {
    __shared__ float t[32][33];
    int tx = threadIdx.x, ty = threadIdx.y;
    int n = blockIdx.x * 32 + tx, b = blockIdx.y * 32 + ty;
    if (n < N_ALL) t[ty][tx] = x[b * N_ALL + n];
    __syncthreads();
    int n2 = blockIdx.x * 32 + ty, b2 = blockIdx.y * 32 + tx;
    if (n2 < N_ALL) xT[n2 * B + b2] = t[tx][ty];
}

// base[n][c][b] = sum_{FF+IF e->n} w1[e][c]*x[src_e][b] + b1[n*C+c]; bb[n][c] = sum w1[e][c]*b2[e]
__global__ void k_base(const float* __restrict__ xT, const float* __restrict__ w1,
                       const float* __restrict__ b1, const float* __restrict__ b2,
                       const int* __restrict__ rsA, const int* __restrict__ eidA,
                       const int* __restrict__ srcv,
                       float* __restrict__ baseG, float* __restrict__ bbG) {
    int n = blockIdx.x, tid = threadIdx.x;
    int beg = rsA[n], end = rsA[n + 1];
    float acc[C] = {0.f,0.f,0.f,0.f,0.f,0.f,0.f,0.f};
    float bba[C] = {0.f,0.f,0.f,0.f,0.f,0.f,0.f,0.f};
    const float4* w14 = (const float4*)w1;
    for (int a = beg; a < end; ++a) {
        int e = eidA[a];
        float xv = xT[srcv[e] * B + tid];
        float bv = b2[e];
        float4 u0 = w14[e * 2], u1 = w14[e * 2 + 1];
        acc[0] += u0.x * xv; acc[1] += u0.y * xv; acc[2] += u0.z * xv; acc[3] += u0.w * xv;
        acc[4] += u1.x * xv; acc[5] += u1.y * xv; acc[6] += u1.z * xv; acc[7] += u1.w * xv;
        bba[0] += u0.x * bv; bba[1] += u0.y * bv; bba[2] += u0.z * bv; bba[3] += u0.w * bv;
        bba[4] += u1.x * bv; bba[5] += u1.y * bv; bba[6] += u1.z * bv; bba[7] += u1.w * bv;
    }
    #pragma unroll
    for (int c = 0; c < C; ++c) baseG[(n * C + c) * B + tid] = acc[c] + b1[n * C + c];
    if (tid == 0) {
        #pragma unroll
        for (int c = 0; c < C; ++c) bbG[n * C + c] = bba[c];
    }
}

// ---------------- per-layer pipeline (bf16 q and hid) ----------------
// hid_t[n] = base[n] + t*bb[n] + sum_{FF e->n} w1[e]*q_t[e],  q_t[e] = w2[e].S_t[src_e]
// S_t = sum over layers < t of normalized+ELU hidden.

__global__ void f_hidstat(const float* __restrict__ baseG, const float* __restrict__ bbG,
                          const float* __restrict__ w1, const unsigned short* __restrict__ qbf,
                          const int* __restrict__ rsB, const int* __restrict__ eidB,
                          unsigned short* __restrict__ hidbf, float* __restrict__ bp, int t) {
    int blk = blockIdx.x, tid = threadIdx.x;
    const float4* w14 = (const float4*)w1;
    float tf = (float)t;
    float s1 = 0.f, s2 = 0.f;
    for (int u = 0; u < NPB; ++u) {
        int n = blk * NPB + u;
        float hid[C];
        #pragma unroll
        for (int c = 0; c < C; ++c) hid[c] = baseG[(n * C + c) * B + tid] + tf * bbG[n * C + c];
        if (t > 0) {
            int beg = rsB[n], end = rsB[n + 1];
            for (int j = beg; j < end; ++j) {
                int e = eidB[j];
                float qv = bf2f(qbf[e * B + tid]);
                float4 u0 = w14[e * 2], u1 = w14[e * 2 + 1];
                hid[0] += u0.x * qv; hid[1] += u0.y * qv; hid[2] += u0.z * qv; hid[3] += u0.w * qv;
                hid[4] += u1.x * qv; hid[5] += u1.y * qv; hid[6] += u1.z * qv; hid[7] += u1.w * qv;
            }
        }
        #pragma unroll
        for (int c = 0; c < C; ++c) {
            hidbf[(n * C + c) * B + tid] = f2bf(hid[c]);
            s1 += hid[c]; s2 += hid[c] * hid[c];
        }
    }
    bp[(blk * 2 + 0) * B + tid] = s1;
    bp[(blk * 2 + 1) * B + tid] = s2;
}

__global__ void f_red(const float* __restrict__ bp, float* __restrict__ p2) {
    int blk = blockIdx.x, tid = threadIdx.x;
    float a1 = 0.f, a2 = 0.f;
    for (int i = blk; i < NBLK; i += 8) {
        a1 += bp[(i * 2 + 0) * B + tid];
        a2 += bp[(i * 2 + 1) * B + tid];
    }
    p2[(blk * 2 + 0) * B + tid] = a1;
    p2[(blk * 2 + 1) * B + tid] = a2;
}

__global__ void f_upd(const unsigned short* __restrict__ hidbf, const float* __restrict__ p2,
                      const float* __restrict__ gamma, const float* __restrict__ beta,
                      const float* __restrict__ w2, const int* __restrict__ rsC,
                      const int* __restrict__ eidC,
                      float* __restrict__ Sg, unsigned short* __restrict__ qbf, int t) {
    int blk = blockIdx.x, tid = threadIdx.x;
    const float4* w24 = (const float4*)w2;
    float S1 = 0.f, S2 = 0.f;
    #pragma unroll
    for (int k = 0; k < 8; ++k) {
        S1 += p2[(k * 2 + 0) * B + tid];
        S2 += p2[(k * 2 + 1) * B + tid];
    }
    float mu  = S1 * (1.0f / H);
    float var = S2 * (1.0f / H) - mu * mu;
    float rsq = rsqrtf(var + EPSF);
    for (int u = 0; u < NPB; ++u) {
        int n = blk * NPB + u;
        float Sn[C];
        #pragma unroll
        for (int c = 0; c < C; ++c) {
            float v = bf2f(hidbf[(n * C + c) * B + tid]);
            v = (v - mu) * rsq * gamma[n * C + c] + beta[n * C + c];
            v = (v > 0.f) ? v : expm1f(v);
            Sn[c] = (t == 0) ? v : (Sg[(n * C + c) * B + tid] + v);
        }
        #pragma unroll
        for (int c = 0; c < C; ++c) Sg[(n * C + c) * B + tid] = Sn[c];
        if (t < LAYERS - 1) {
            int beg = rsC[n], end = rsC[n + 1];
            for (int p = beg; p < end; ++p) {
                int e = eidC[p];
                float4 u0 = w24[e * 2], u1 = w24[e * 2 + 1];
                float qv = u0.x * Sn[0] + u0.y * Sn[1] + u0.z * Sn[2] + u0.w * Sn[3]
                         + u1.x * Sn[4] + u1.y * Sn[5] + u1.z * Sn[6] + u1.w * Sn[7];
                qbf[e * B + tid] = f2bf(qv);
            }
        }
    }
}

// ---------------- output ----------------

__global__ void f_zero_out(float* __restrict__ out) {
    int i = blockIdx.x * 256 + threadIdx.x;  // 750*256 float4 = 768000 floats
    ((float4*)out)[i] = make_float4(0.f, 0.f, 0.f, 0.f);
}

__global__ void f_out(const float* __restrict__ xT, const float* __restrict__ Sg,
                      const int* __restrict__ rsD, const int* __restrict__ eidD,
                      const int* __restrict__ srcv, const float* __restrict__ w2,
                      const float* __restrict__ b2, float* __restrict__ out) {
    int o = blockIdx.x, tid = threadIdx.x;
    const float4* w24 = (const float4*)w2;
    float acc = 0.f;
    int beg = rsD[o], end = rsD[o + 1];
    for (int k = beg; k < end; ++k) {
        int e = eidD[k];
        int s = srcv[e];
        float4 u0 = w24[e * 2], u1 = w24[e * 2 + 1];
        float dot = u0.x * Sg[(s * C + 0) * B + tid] + u0.y * Sg[(s * C + 1) * B + tid]
                  + u0.z * Sg[(s * C + 2) * B + tid] + u0.w * Sg[(s * C + 3) * B + tid]
                  + u1.x * Sg[(s * C + 4) * B + tid] + u1.y * Sg[(s * C + 5) * B + tid]
                  + u1.z * Sg[(s * C + 6) * B + tid] + u1.w * Sg[(s * C + 7) * B + tid];
        acc += xT[s * B + tid] + dot + (float)LAYERS * b2[e];
    }
    out[tid * N_ALL + (N_F + N_I + o)] = acc * (1.0f / LAYERS);
}

// ---------------- launch ----------------

static inline char* alignup(char* p) { return (char*)(((uintptr_t)p + 255) & ~(uintptr_t)255); }

extern "C" void kernel_launch(void* const* d_in, const int* in_sizes, int n_in,
                              void* d_out, int out_size, void* d_ws, size_t ws_size,
                              hipStream_t stream) {
    const float* x     = (const float*)d_in[0];
    const float* w1    = (const float*)d_in[1];
    const float* b1    = (const float*)d_in[2];
    const float* gamma = (const float*)d_in[3];
    const float* beta  = (const float*)d_in[4];
    const float* w2    = (const float*)d_in[5];
    const float* b2    = (const float*)d_in[6];
    const int*   ei    = (const int*)d_in[7];
    const int* srcv = ei;
    const int* dstv = ei + E_ALL;
    float* out = (float*)d_out;

    char* p = (char*)d_ws;
    unsigned short* qbf   = (unsigned short*)p; p += (size_t)E_FF * B * 2; p = alignup(p);
    unsigned short* hidbf = (unsigned short*)p; p += (size_t)H * B * 2;    p = alignup(p);
    float* Sg    = (float*)p; p += (size_t)H * B * 4;       p = alignup(p);
    float* baseG = (float*)p; p += (size_t)H * B * 4;       p = alignup(p);
    float* xT    = (float*)p; p += (size_t)N_ALL * B * 4;   p = alignup(p);
    float* bp    = (float*)p; p += (size_t)NBLK * 2 * B * 4; p = alignup(p);
    float* p2    = (float*)p; p += 8 * 2 * B * 4;           p = alignup(p);
    float* bbG   = (float*)p; p += (size_t)N_F * C * 4;     p = alignup(p);
    int* cntA = (int*)p; p += N_F * 4;        p = alignup(p);
    int* cntB = (int*)p; p += N_F * 4;        p = alignup(p);
    int* cntC = (int*)p; p += N_F * 4;        p = alignup(p);
    int* cntD = (int*)p; p += N_O * 4;        p = alignup(p);
    int* curA = (int*)p; p += N_F * 4;        p = alignup(p);
    int* curB = (int*)p; p += N_F * 4;        p = alignup(p);
    int* curC = (int*)p; p += N_F * 4;        p = alignup(p);
    int* curD = (int*)p; p += N_O * 4;        p = alignup(p);
    int* rsA  = (int*)p; p += (N_F + 1) * 4;  p = alignup(p);
    int* rsB  = (int*)p; p += (N_F + 1) * 4;  p = alignup(p);
    int* rsC  = (int*)p; p += (N_F + 1) * 4;  p = alignup(p);
    int* rsD  = (int*)p; p += (N_O + 1) * 4;  p = alignup(p);
    int* eidA = (int*)p; p += (size_t)(E_FF + E_IF) * 4; p = alignup(p);
    int* eidB = (int*)p; p += (size_t)E_FF * 4; p = alignup(p);
    int* eidC = (int*)p; p += (size_t)E_FF * 4; p = alignup(p);
    int* eidD = (int*)p; p += (size_t)E_FO * 4; p = alignup(p);

    hipLaunchKernelGGL(k_zero_cnt, dim3(1), dim3(1024), 0, stream, cntA, cntB, cntC, cntD);
    hipLaunchKernelGGL(k_count, dim3((E_ALL + 255) / 256), dim3(256), 0, stream,
                       srcv, dstv, cntA, cntB, cntC, cntD);
    hipLaunchKernelGGL(k_scan, dim3(4), dim3(1024), 0, stream,
                       cntA, cntB, cntC, cntD, rsA, rsB, rsC, rsD, curA, curB, curC, curD);
    hipLaunchKernelGGL(k_fill, dim3((E_ALL + 255) / 256), dim3(256), 0, stream,
                       srcv, dstv, curA, curB, curC, curD, eidA, eidB, eidC, eidD);
    hipLaunchKernelGGL(k_sort, dim3(26), dim3(256), 0, stream,
                       rsA, eidA, rsB, eidB, rsC, eidC, rsD, eidD);
    hipLaunchKernelGGL(k_xT, dim3((N_ALL + 31) / 32, B / 32), dim3(32, 32), 0, stream, x, xT);
    hipLaunchKernelGGL(k_base, dim3(N_F), dim3(256), 0, stream,
                       xT, w1, b1, b2, rsA, eidA, srcv, baseG, bbG);

    hipLaunchKernelGGL(f_zero_out, dim3(750), dim3(256), 0, stream, out);
    for (int t = 0; t < LAYERS; ++t) {
        hipLaunchKernelGGL(f_hidstat, dim3(NBLK), dim3(256), 0, stream,
                           baseG, bbG, w1, qbf, rsB, eidB, hidbf, bp, t);
        hipLaunchKernelGGL(f_red, dim3(8), dim3(256), 0, stream, bp, p2);
        hipLaunchKernelGGL(f_upd, dim3(NBLK), dim3(256), 0, stream,
                           hidbf, p2, gamma, beta, w2, rsC, eidC, Sg, qbf, t);
    }
    hipLaunchKernelGGL(f_out, dim3(N_O), dim3(256), 0, stream,
                       xT, Sg, rsD, eidD, srcv, w2, b2, out);
}

// Round 7
// 742.318 us; speedup vs baseline: 1.6193x; 1.5737x over previous
//
#include <hip/hip_runtime.h>
#include <cmath>
#include <cstdint>

#define N_F    2000
#define N_I    500
#define N_O    500
#define N_ALL  3000
#define C      8
#define H      16000
#define B      256
#define E_FF   40000
#define E_IF   5000
#define E_FO   2000
#define E_ALL  47000
#define LAYERS 10
#define EPSF   1e-5f
#define RED    32     // f_red blocks / p2 slices

// ---- bf16 helpers (RNE) ----
static __device__ __forceinline__ unsigned short f2bf(float f) {
    unsigned int u = __float_as_uint(f);
    unsigned int r = (u + 0x7FFFu + ((u >> 16) & 1u)) >> 16;
    return (unsigned short)r;
}
static __device__ __forceinline__ float bf2f(unsigned short h) {
    return __uint_as_float(((unsigned int)h) << 16);
}

// ---------------- CSR build (deterministic after k_wsort) ----------------

__global__ void k_zero_cnt(int* cntA, int* cntB, int* cntC, int* cntD) {
    int tid = threadIdx.x;
    for (int i = tid; i < N_F; i += 1024) { cntA[i] = 0; cntB[i] = 0; cntC[i] = 0; }
    for (int i = tid; i < N_O; i += 1024) cntD[i] = 0;
}

__global__ void k_count(const int* __restrict__ src, const int* __restrict__ dst,
                        int* cntA, int* cntB, int* cntC, int* cntD) {
    int e = blockIdx.x * 256 + threadIdx.x;
    if (e >= E_ALL) return;
    int s = src[e], d = dst[e];
    if (e < E_FF)             { atomicAdd(&cntA[d], 1); atomicAdd(&cntB[d], 1); atomicAdd(&cntC[s], 1); }
    else if (e < E_FF + E_IF) { atomicAdd(&cntA[d], 1); }
    else                      { atomicAdd(&cntD[d - (N_F + N_I)], 1); }
}

// 3 single-block scans: A(dst,FF+IF), C(src,FF), D(dst,FO)
__global__ void k_scan(const int* cntA, const int* cntC, const int* cntD,
                       int* rsA, int* rsC, int* rsD,
                       int* curA, int* curC, int* curD) {
    const int* cnt; int* rs; int* cur; int len;
    if      (blockIdx.x == 0) { cnt = cntA; rs = rsA; cur = curA; len = N_F; }
    else if (blockIdx.x == 1) { cnt = cntC; rs = rsC; cur = curC; len = N_F; }
    else                      { cnt = cntD; rs = rsD; cur = curD; len = N_O; }
    __shared__ int buf[1024];
    __shared__ int carry;
    int tid = threadIdx.x;
    if (tid == 0) carry = 0;
    __syncthreads();
    for (int base0 = 0; base0 < len; base0 += 1024) {
        int i = base0 + tid;
        int v = (i < len) ? cnt[i] : 0;
        buf[tid] = v;
        __syncthreads();
        for (int off = 1; off < 1024; off <<= 1) {
            int t = (tid >= off) ? buf[tid - off] : 0;
            __syncthreads();
            buf[tid] += t;
            __syncthreads();
        }
        int excl = carry + buf[tid] - v;
        if (i < len) { rs[i] = excl; cur[i] = excl; }
        int tot = buf[1023];
        __syncthreads();
        if (tid == 0) carry += tot;
        __syncthreads();
    }
    if (tid == 0) rs[len] = carry;
}

__global__ void k_fill(const int* __restrict__ src, const int* __restrict__ dst,
                       int* curA, int* curC, int* curD,
                       int* eidA, int* eidC, int* eidD) {
    int e = blockIdx.x * 256 + threadIdx.x;
    if (e >= E_ALL) return;
    int s = src[e], d = dst[e];
    if (e < E_FF) {
        int a = atomicAdd(&curA[d], 1); eidA[a] = e;
        int p = atomicAdd(&curC[s], 1); eidC[p] = e;
    } else if (e < E_FF + E_IF) {
        int a = atomicAdd(&curA[d], 1); eidA[a] = e;
    } else {
        int k = atomicAdd(&curD[d - (N_F + N_I)], 1); eidD[k] = e;
    }
}

// canonicalize: wave rank-sort each list ascending by edge id.
// One 64-lane wave per list; rank via shfl comparisons. Lists: A(2000), C(2000), D(500).
__global__ void k_wsort(const int* __restrict__ rsA, int* eidA,
                        const int* __restrict__ rsC, int* eidC,
                        const int* __restrict__ rsD, int* eidD) {
    int w = blockIdx.x * 4 + (threadIdx.x >> 6);
    int lane = threadIdx.x & 63;
    const int* rs; int* eid; int n;
    if      (w < 2000) { rs = rsA; eid = eidA; n = w; }
    else if (w < 4000) { rs = rsC; eid = eidC; n = w - 2000; }
    else if (w < 4500) { rs = rsD; eid = eidD; n = w - 4000; }
    else return;
    int beg = rs[n], end = rs[n + 1], len = end - beg;
    if (len <= 1) return;
    if (len <= 64) {
        int v = (lane < len) ? eid[beg + lane] : 0x7fffffff;
        int rank = 0;
        for (int j = 0; j < 64; ++j) {
            int o = __shfl(v, j, 64);
            rank += (o < v) ? 1 : 0;
        }
        if (lane < len) eid[beg + rank] = v;
    } else if (lane == 0) {
        for (int i = beg + 1; i < end; ++i) {
            int key = eid[i];
            int j = i - 1;
            while (j >= beg && eid[j] > key) { eid[j + 1] = eid[j]; --j; }
            eid[j + 1] = key;
        }
    }
}

// ---------------- init ----------------

// x (B, N_ALL) -> xT (N_ALL, B)
__global__ void k_xT(const float* __restrict__ x, float* __restrict__ xT) {
    __shared__ float t[32][33];
    int tx = threadIdx.x, ty = threadIdx.y;
    int n = blockIdx.x * 32 + tx, b = blockIdx.y * 32 + ty;
    if (n < N_ALL) t[ty][tx] = x[b * N_ALL + n];
    __syncthreads();
    int n2 = blockIdx.x * 32 + ty, b2 = blockIdx.y * 32 + tx;
    if (n2 < N_ALL) xT[n2 * B + b2] = t[tx][ty];
}

// base[n][c][b] = sum_{FF+IF e->n} w1[e][c]*x[src_e][b] + b1[n*C+c]; bb[n][c] = sum w1[e][c]*b2[e]
__global__ void k_base(const float* __restrict__ xT, const float* __restrict__ w1,
                       const float* __restrict__ b1, const float* __restrict__ b2,
                       const int* __restrict__ rsA, const int* __restrict__ eidA,
                       const int* __restrict__ srcv,
                       float* __restrict__ baseG, float* __restrict__ bbG) {
    int n = blockIdx.x, tid = threadIdx.x;
    int beg = rsA[n], end = rsA[n + 1];
    float acc[C] = {0.f,0.f,0.f,0.f,0.f,0.f,0.f,0.f};
    float bba[C] = {0.f,0.f,0.f,0.f,0.f,0.f,0.f,0.f};
    const float4* w14 = (const float4*)w1;
    for (int a = beg; a < end; ++a) {
        int e = eidA[a];
        float xv = xT[srcv[e] * B + tid];
        float bv = b2[e];
        float4 u0 = w14[e * 2], u1 = w14[e * 2 + 1];
        acc[0] += u0.x * xv; acc[1] += u0.y * xv; acc[2] += u0.z * xv; acc[3] += u0.w * xv;
        acc[4] += u1.x * xv; acc[5] += u1.y * xv; acc[6] += u1.z * xv; acc[7] += u1.w * xv;
        bba[0] += u0.x * bv; bba[1] += u0.y * bv; bba[2] += u0.z * bv; bba[3] += u0.w * bv;
        bba[4] += u1.x * bv; bba[5] += u1.y * bv; bba[6] += u1.z * bv; bba[7] += u1.w * bv;
    }
    #pragma unroll
    for (int c = 0; c < C; ++c) baseG[(n * C + c) * B + tid] = acc[c] + b1[n * C + c];
    if (tid == 0) {
        #pragma unroll
        for (int c = 0; c < C; ++c) bbG[n * C + c] = bba[c];
    }
}

// ---------------- per-layer pipeline (bf16 q and hid) ----------------
// hid_t[n] = base[n] + t*bb[n] + sum_{FF e->n} w1[e]*q_t[e],  q_t[e] = w2[e].S_t[src_e]
// FF edges = first cntB[n] entries of the (sorted) A-list.

__global__ void f_hidstat(const float* __restrict__ baseG, const float* __restrict__ bbG,
                          const float* __restrict__ w1, const unsigned short* __restrict__ qbf,
                          const int* __restrict__ rsA, const int* __restrict__ eidA,
                          const int* __restrict__ cntB,
                          unsigned short* __restrict__ hidbf, float* __restrict__ bp, int t) {
    int n = blockIdx.x, tid = threadIdx.x;
    const float4* w14 = (const float4*)w1;
    float tf = (float)t;
    float hid[C];
    #pragma unroll
    for (int c = 0; c < C; ++c) hid[c] = baseG[(n * C + c) * B + tid] + tf * bbG[n * C + c];
    if (t > 0) {
        int beg = rsA[n], m = cntB[n];
        for (int j = beg; j < beg + m; ++j) {
            int e = eidA[j];
            float qv = bf2f(qbf[e * B + tid]);
            float4 u0 = w14[e * 2], u1 = w14[e * 2 + 1];
            hid[0] += u0.x * qv; hid[1] += u0.y * qv; hid[2] += u0.z * qv; hid[3] += u0.w * qv;
            hid[4] += u1.x * qv; hid[5] += u1.y * qv; hid[6] += u1.z * qv; hid[7] += u1.w * qv;
        }
    }
    float s1 = 0.f, s2 = 0.f;
    #pragma unroll
    for (int c = 0; c < C; ++c) {
        hidbf[(n * C + c) * B + tid] = f2bf(hid[c]);
        s1 += hid[c]; s2 += hid[c] * hid[c];
    }
    bp[(n * 2 + 0) * B + tid] = s1;
    bp[(n * 2 + 1) * B + tid] = s2;
}

// 32 blocks: slice k reduces nodes {k, k+32, ...} (fixed order -> deterministic)
__global__ void f_red(const float* __restrict__ bp, float* __restrict__ p2) {
    int blk = blockIdx.x, tid = threadIdx.x;
    float a1 = 0.f, a2 = 0.f;
    for (int i = blk; i < N_F; i += RED) {
        a1 += bp[(i * 2 + 0) * B + tid];
        a2 += bp[(i * 2 + 1) * B + tid];
    }
    p2[(blk * 2 + 0) * B + tid] = a1;
    p2[(blk * 2 + 1) * B + tid] = a2;
}

__global__ void f_upd(const unsigned short* __restrict__ hidbf, const float* __restrict__ p2,
                      const float* __restrict__ gamma, const float* __restrict__ beta,
                      const float* __restrict__ w2, const int* __restrict__ rsC,
                      const int* __restrict__ eidC,
                      float* __restrict__ Sg, unsigned short* __restrict__ qbf, int t) {
    int n = blockIdx.x, tid = threadIdx.x;
    const float4* w24 = (const float4*)w2;
    float S1 = 0.f, S2 = 0.f;
    #pragma unroll
    for (int k = 0; k < RED; ++k) {
        S1 += p2[(k * 2 + 0) * B + tid];
        S2 += p2[(k * 2 + 1) * B + tid];
    }
    float mu  = S1 * (1.0f / H);
    float var = S2 * (1.0f / H) - mu * mu;
    float rsq = rsqrtf(var + EPSF);
    float Sn[C];
    #pragma unroll
    for (int c = 0; c < C; ++c) {
        float v = bf2f(hidbf[(n * C + c) * B + tid]);
        v = (v - mu) * rsq * gamma[n * C + c] + beta[n * C + c];
        v = (v > 0.f) ? v : expm1f(v);
        Sn[c] = (t == 0) ? v : (Sg[(n * C + c) * B + tid] + v);
    }
    #pragma unroll
    for (int c = 0; c < C; ++c) Sg[(n * C + c) * B + tid] = Sn[c];
    if (t < LAYERS - 1) {
        int beg = rsC[n], end = rsC[n + 1];
        for (int p = beg; p < end; ++p) {
            int e = eidC[p];
            float4 u0 = w24[e * 2], u1 = w24[e * 2 + 1];
            float qv = u0.x * Sn[0] + u0.y * Sn[1] + u0.z * Sn[2] + u0.w * Sn[3]
                     + u1.x * Sn[4] + u1.y * Sn[5] + u1.z * Sn[6] + u1.w * Sn[7];
            qbf[e * B + tid] = f2bf(qv);
        }
    }
}

// ---------------- output ----------------

__global__ void f_zero_out(float* __restrict__ out) {
    int i = blockIdx.x * 256 + threadIdx.x;  // 750*256 float4 = 768000 floats
    ((float4*)out)[i] = make_float4(0.f, 0.f, 0.f, 0.f);
}

__global__ void f_out(const float* __restrict__ xT, const float* __restrict__ Sg,
                      const int* __restrict__ rsD, const int* __restrict__ eidD,
                      const int* __restrict__ srcv, const float* __restrict__ w2,
                      const float* __restrict__ b2, float* __restrict__ out) {
    int o = blockIdx.x, tid = threadIdx.x;
    const float4* w24 = (const float4*)w2;
    float acc = 0.f;
    int beg = rsD[o], end = rsD[o + 1];
    for (int k = beg; k < end; ++k) {
        int e = eidD[k];
        int s = srcv[e];
        float4 u0 = w24[e * 2], u1 = w24[e * 2 + 1];
        float dot = u0.x * Sg[(s * C + 0) * B + tid] + u0.y * Sg[(s * C + 1) * B + tid]
                  + u0.z * Sg[(s * C + 2) * B + tid] + u0.w * Sg[(s * C + 3) * B + tid]
                  + u1.x * Sg[(s * C + 4) * B + tid] + u1.y * Sg[(s * C + 5) * B + tid]
                  + u1.z * Sg[(s * C + 6) * B + tid] + u1.w * Sg[(s * C + 7) * B + tid];
        acc += xT[s * B + tid] + dot + (float)LAYERS * b2[e];
    }
    out[tid * N_ALL + (N_F + N_I + o)] = acc * (1.0f / LAYERS);
}

// ---------------- launch ----------------

static inline char* alignup(char* p) { return (char*)(((uintptr_t)p + 255) & ~(uintptr_t)255); }

extern "C" void kernel_launch(void* const* d_in, const int* in_sizes, int n_in,
                              void* d_out, int out_size, void* d_ws, size_t ws_size,
                              hipStream_t stream) {
    const float* x     = (const float*)d_in[0];
    const float* w1    = (const float*)d_in[1];
    const float* b1    = (const float*)d_in[2];
    const float* gamma = (const float*)d_in[3];
    const float* beta  = (const float*)d_in[4];
    const float* w2    = (const float*)d_in[5];
    const float* b2    = (const float*)d_in[6];
    const int*   ei    = (const int*)d_in[7];
    const int* srcv = ei;
    const int* dstv = ei + E_ALL;
    float* out = (float*)d_out;

    char* p = (char*)d_ws;
    unsigned short* qbf   = (unsigned short*)p; p += (size_t)E_FF * B * 2; p = alignup(p);
    unsigned short* hidbf = (unsigned short*)p; p += (size_t)H * B * 2;    p = alignup(p);
    float* Sg    = (float*)p; p += (size_t)H * B * 4;        p = alignup(p);
    float* baseG = (float*)p; p += (size_t)H * B * 4;        p = alignup(p);
    float* xT    = (float*)p; p += (size_t)N_ALL * B * 4;    p = alignup(p);
    float* bp    = (float*)p; p += (size_t)N_F * 2 * B * 4;  p = alignup(p);
    float* p2    = (float*)p; p += (size_t)RED * 2 * B * 4;  p = alignup(p);
    float* bbG   = (float*)p; p += (size_t)N_F * C * 4;      p = alignup(p);
    int* cntA = (int*)p; p += N_F * 4;        p = alignup(p);
    int* cntB = (int*)p; p += N_F * 4;        p = alignup(p);
    int* cntC = (int*)p; p += N_F * 4;        p = alignup(p);
    int* cntD = (int*)p; p += N_O * 4;        p = alignup(p);
    int* curA = (int*)p; p += N_F * 4;        p = alignup(p);
    int* curC = (int*)p; p += N_F * 4;        p = alignup(p);
    int* curD = (int*)p; p += N_O * 4;        p = alignup(p);
    int* rsA  = (int*)p; p += (N_F + 1) * 4;  p = alignup(p);
    int* rsC  = (int*)p; p += (N_F + 1) * 4;  p = alignup(p);
    int* rsD  = (int*)p; p += (N_O + 1) * 4;  p = alignup(p);
    int* eidA = (int*)p; p += (size_t)(E_FF + E_IF) * 4; p = alignup(p);
    int* eidC = (int*)p; p += (size_t)E_FF * 4; p = alignup(p);
    int* eidD = (int*)p; p += (size_t)E_FO * 4; p = alignup(p);

    hipLaunchKernelGGL(k_zero_cnt, dim3(1), dim3(1024), 0, stream, cntA, cntB, cntC, cntD);
    hipLaunchKernelGGL(k_count, dim3((E_ALL + 255) / 256), dim3(256), 0, stream,
                       srcv, dstv, cntA, cntB, cntC, cntD);
    hipLaunchKernelGGL(k_scan, dim3(3), dim3(1024), 0, stream,
                       cntA, cntC, cntD, rsA, rsC, rsD, curA, curC, curD);
    hipLaunchKernelGGL(k_fill, dim3((E_ALL + 255) / 256), dim3(256), 0, stream,
                       srcv, dstv, curA, curC, curD, eidA, eidC, eidD);
    hipLaunchKernelGGL(k_wsort, dim3(1125), dim3(256), 0, stream,
                       rsA, eidA, rsC, eidC, rsD, eidD);
    hipLaunchKernelGGL(k_xT, dim3((N_ALL + 31) / 32, B / 32), dim3(32, 32), 0, stream, x, xT);
    hipLaunchKernelGGL(k_base, dim3(N_F), dim3(256), 0, stream,
                       xT, w1, b1, b2, rsA, eidA, srcv, baseG, bbG);

    hipLaunchKernelGGL(f_zero_out, dim3(750), dim3(256), 0, stream, out);
    for (int t = 0; t < LAYERS; ++t) {
        hipLaunchKernelGGL(f_hidstat, dim3(N_F), dim3(256), 0, stream,
                           baseG, bbG, w1, qbf, rsA, eidA, cntB, hidbf, bp, t);
        hipLaunchKernelGGL(f_red, dim3(RED), dim3(256), 0, stream, bp, p2);
        hipLaunchKernelGGL(f_upd, dim3(N_F), dim3(256), 0, stream,
                           hidbf, p2, gamma, beta, w2, rsC, eidC, Sg, qbf, t);
    }
    hipLaunchKernelGGL(f_out, dim3(N_O), dim3(256), 0, stream,
                       xT, Sg, rsD, eidD, srcv, w2, b2, out);
}